// Round 22
// baseline (31.313 us; speedup 1.0000x reference)
//
#include <hip/hip_runtime.h>

#define IMG   512
#define NCLS  256
#define DIM   1024
#define HPW   32
#define TPB   16           // tokens per block = full MFMA M
#define NT    1024         // 16 waves; wave owns 64 dims
#define MAGIC 0x5EEDC0DEu

typedef short bf16x8 __attribute__((ext_vector_type(8)));
typedef float f32x4  __attribute__((ext_vector_type(4)));

__device__ inline ushort bf16rne(float v) {
    unsigned u = __float_as_uint(v);
    return (ushort)((u + 0x7fffu + ((u >> 16) & 1u)) >> 16);
}

// R16 skeleton (best: 19.2 us). Single change: the global 128-flag gate is
// replaced by a PER-WAVE gate on the 8 flags covering that wave's 4 dtiles,
// so each wave starts its GEMM as soon as ITS producers are done.
//   Tt2[dtile*4096 + ks*512 + g*128 + c*8 + j] = bf16(table[ks*32+g*8+j][dtile*16+c])
//   dtile covered by blocks {2*dtile, 2*dtile+1} -> wave w needs flags 8w..8w+7.
__global__ __launch_bounds__(NT)
void fused_one(const int* __restrict__ smap, const float* __restrict__ table,
               const float* __restrict__ gamma, const float* __restrict__ beta,
               float* __restrict__ out, ushort* __restrict__ Tt2,
               unsigned* __restrict__ flags)
{
    __shared__ unsigned cnt[TPB * NCLS];      // 16 KB
    __shared__ ushort   pk[2048];             // 4 KB pack staging
    __shared__ ushort   cntb[16][264];        // stride 528 B -> conflict-free b128
    __shared__ float    red[16][4][4][2];     // [wave][g][i][{s,s2}]

    const int t    = threadIdx.x;
    const int lane = t & 63;
    const int w    = t >> 6;
    const int c    = lane & 15;
    const int g    = lane >> 4;

    const int bid  = blockIdx.x;
    const int tok0 = bid * TPB;
    const int b    = tok0 >> 10;
    const int ph   = (tok0 >> 5) & 31;
    const int pw0  = tok0 & 31;               // 0 or 16

    const int dtile = bid >> 1;
    const int kh    = bid & 1;

    // ---- 1) pack-load: 128 cls x 16 dims -> LDS scatter (fragment order) ----
    if (t < 512) {
        const int cls  = kh * 128 + (t >> 2);
        const int quad = t & 3;
        const float4 v = *reinterpret_cast<const float4*>(
            table + (size_t)cls * DIM + dtile * 16 + quad * 4);
        const int ks = cls >> 5, gg = (cls >> 3) & 3, j = cls & 7;
        ushort* dst = pk + (ks & 3) * 512 + gg * 128 + j;
        dst[(quad * 4 + 0) * 8] = bf16rne(v.x);
        dst[(quad * 4 + 1) * 8] = bf16rne(v.y);
        dst[(quad * 4 + 2) * 8] = bf16rne(v.z);
        dst[(quad * 4 + 3) * 8] = bf16rne(v.w);
    }
    // ---- 2) zero hist ----
    for (int i = t; i < TPB * NCLS; i += NT) cnt[i] = 0u;
    __syncthreads();

    // ---- 3) pack copy-out: system-scope atomic dwords (bypass L2 -> coherent) ----
    {
        const unsigned val = (unsigned)pk[t * 2] | ((unsigned)pk[t * 2 + 1] << 16);
        __hip_atomic_store((unsigned*)Tt2 + (size_t)dtile * 2048 + kh * 1024 + t, val,
                           __ATOMIC_RELAXED, __HIP_MEMORY_SCOPE_SYSTEM);
    }
    __syncthreads();                          // drains every wave's stores (vmcnt 0)

    // ---- 4) publish pack completion (system-scope release) ----
    if (t == 0)
        __hip_atomic_store(&flags[bid], MAGIC, __ATOMIC_RELEASE, __HIP_MEMORY_SCOPE_SYSTEM);

    // ---- 5) histogram: 16 rows x 256 cols (16 patches), int4 per thread ----
    {
        const int row = t >> 6;               // 0..15
        const int col = (t & 63) * 4;         // 0..252
        const int4 q = *reinterpret_cast<const int4*>(
            smap + ((size_t)b * IMG + (size_t)(ph * 16 + row)) * IMG + pw0 * 16 + col);
        unsigned* hp = &cnt[(col >> 4) * NCLS];
        atomicAdd(&hp[min(max(q.x, 0), NCLS - 1)], 1u);
        atomicAdd(&hp[min(max(q.y, 0), NCLS - 1)], 1u);
        atomicAdd(&hp[min(max(q.z, 0), NCLS - 1)], 1u);
        atomicAdd(&hp[min(max(q.w, 0), NCLS - 1)], 1u);
    }
    __syncthreads();

    // ---- 6) counts -> bf16(count/256), exact ----
    for (int i = t; i < TPB * NCLS; i += NT)
        cntb[i >> 8][i & 255] = (ushort)(__float_as_uint((float)cnt[i] * (1.f / 256.f)) >> 16);
    __syncthreads();                          // cntb complete (read by every wave)

    // ---- 7) PER-WAVE gate: poll this wave's 8 producer flags (relaxed),
    //         then one acquire load (wave-level cache-inv) before Tt2 reads ----
    {
        if (lane < 8) {
            const int fl = w * 8 + lane;
            while (__hip_atomic_load(&flags[fl], __ATOMIC_RELAXED,
                                     __HIP_MEMORY_SCOPE_SYSTEM) != MAGIC) {}
        }
        const unsigned x = __hip_atomic_load(&flags[w * 8], __ATOMIC_ACQUIRE,
                                             __HIP_MEMORY_SCOPE_SYSTEM);
        asm volatile("" :: "v"(x));           // keep the acquire load live
    }

    // ---- 8) MFMA K-loop (verbatim R16) ----
    f32x4 acc[4];
    #pragma unroll
    for (int i = 0; i < 4; ++i) acc[i] = (f32x4){0.f, 0.f, 0.f, 0.f};

    const ushort* bt = Tt2 + (size_t)(w * 4) * 4096 + (size_t)lane * 8;
    #pragma unroll 2
    for (int ks = 0; ks < 8; ++ks) {
        const bf16x8 a = *reinterpret_cast<const bf16x8*>(&cntb[c][ks * 32 + g * 8]);
        bf16x8 bfv[4];
        #pragma unroll
        for (int nf = 0; nf < 4; ++nf)
            bfv[nf] = *reinterpret_cast<const bf16x8*>(bt + (size_t)nf * 4096 + ks * 512);
        #pragma unroll
        for (int nf = 0; nf < 4; ++nf)
            acc[nf] = __builtin_amdgcn_mfma_f32_16x16x32_bf16(a, bfv[nf], acc[nf], 0, 0, 0);
    }

    // ---- 9) pos-embed + LN partials (verbatim R16) ----
    const int quad   = w >> 2;
    const int cosSel = quad & 1;
    float ls[4]  = {0, 0, 0, 0};
    float ls2[4] = {0, 0, 0, 0};

    #pragma unroll
    for (int nf = 0; nf < 4; ++nf) {
        const int dlow = (w & 3) * 64 + nf * 16 + c;
        const float omega = exp2f((float)dlow * (-13.287712379549449f / 256.f));
        if (quad < 2) {
            float sv, cv; __sincosf((float)ph * omega, &sv, &cv);
            const float v = cosSel ? cv : sv;
            #pragma unroll
            for (int i = 0; i < 4; ++i) acc[nf][i] += v;
        } else {
            #pragma unroll
            for (int i = 0; i < 4; ++i) {
                float sv, cv; __sincosf((float)(pw0 + g * 4 + i) * omega, &sv, &cv);
                acc[nf][i] += cosSel ? cv : sv;
            }
        }
        #pragma unroll
        for (int i = 0; i < 4; ++i) { ls[i] += acc[nf][i]; ls2[i] += acc[nf][i] * acc[nf][i]; }
    }

    #pragma unroll
    for (int off = 1; off < 16; off <<= 1) {
        #pragma unroll
        for (int i = 0; i < 4; ++i) {
            ls[i]  += __shfl_xor(ls[i],  off, 64);
            ls2[i] += __shfl_xor(ls2[i], off, 64);
        }
    }
    if (c == 0) {
        #pragma unroll
        for (int i = 0; i < 4; ++i) { red[w][g][i][0] = ls[i]; red[w][g][i][1] = ls2[i]; }
    }
    __syncthreads();

    // ---- 10) finalize LN + store (verbatim R16) ----
    {
        float mu[4], rs[4];
        #pragma unroll
        for (int i = 0; i < 4; ++i) {
            float S = 0.f, S2 = 0.f;
            #pragma unroll
            for (int ww = 0; ww < 16; ++ww) { S += red[ww][g][i][0]; S2 += red[ww][g][i][1]; }
            mu[i] = S * (1.f / DIM);
            rs[i] = rsqrtf(S2 * (1.f / DIM) - mu[i] * mu[i] + 1e-5f);
        }
        #pragma unroll
        for (int nf = 0; nf < 4; ++nf) {
            const int d = w * 64 + nf * 16 + c;
            const float gv = gamma[d], bv = beta[d];
            #pragma unroll
            for (int i = 0; i < 4; ++i) {
                const int r = g * 4 + i;
                out[(size_t)(tok0 + r) * DIM + d] = (acc[nf][i] - mu[i]) * rs[i] * gv + bv;
            }
        }
    }
}

extern "C" void kernel_launch(void* const* d_in, const int* in_sizes, int n_in,
                              void* d_out, int out_size, void* d_ws, size_t ws_size,
                              hipStream_t stream) {
    const int*   smap  = (const int*)d_in[0];
    const float* table = (const float*)d_in[1];
    const float* gamma = (const float*)d_in[2];
    const float* beta  = (const float*)d_in[3];
    float*       out   = (float*)d_out;

    const int batches = in_sizes[0] / (IMG * IMG);       // = 2
    const int tokens  = batches * HPW * HPW;             // 2048
    const int nblk    = tokens / TPB;                    // 128

    ushort*   Tt2   = (ushort*)d_ws;                     // 512 KB packed table
    unsigned* flags = (unsigned*)(Tt2 + (size_t)64 * 4096);

    fused_one<<<nblk, NT, 0, stream>>>(smap, table, gamma, beta, out, Tt2, flags);
}

// Round 23
// 18.747 us; speedup vs baseline: 1.6703x; 1.6703x over previous
//
#include <hip/hip_runtime.h>

#define IMG   512
#define NCLS  256
#define DIM   1024
#define HPW   32
#define TPB   16           // tokens per block = full MFMA M
#define NT    1024         // 16 waves; wave owns 64 dims
#define MAGIC 0x5EEDC0DEu

typedef short bf16x8 __attribute__((ext_vector_type(8)));
typedef float f32x4  __attribute__((ext_vector_type(4)));

__device__ inline ushort bf16rne(float v) {
    unsigned u = __float_as_uint(v);
    return (ushort)((u + 0x7fffu + ((u >> 16) & 1u)) >> 16);
}

// R16 skeleton (best: 19.2 us). SINGLE change vs R16: the gate spins with
// RELAXED loads (no per-poll cache invalidate) and issues ONE acquire after
// the barrier (one buffer_inv per block, before any Tt2 read). R20 proved
// this exact pattern correct; here it is isolated from R20's regressions.
//   Tt2[dtile*4096 + ks*512 + g*128 + c*8 + j] = bf16(table[ks*32+g*8+j][dtile*16+c])
__global__ __launch_bounds__(NT)
void fused_one(const int* __restrict__ smap, const float* __restrict__ table,
               const float* __restrict__ gamma, const float* __restrict__ beta,
               float* __restrict__ out, ushort* __restrict__ Tt2,
               unsigned* __restrict__ flags)
{
    __shared__ unsigned cnt[TPB * NCLS];      // 16 KB
    __shared__ ushort   pk[2048];             // 4 KB pack staging
    __shared__ ushort   cntb[16][264];        // stride 528 B -> conflict-free b128
    __shared__ float    red[16][4][4][2];     // [wave][g][i][{s,s2}]

    const int t    = threadIdx.x;
    const int lane = t & 63;
    const int w    = t >> 6;
    const int c    = lane & 15;
    const int g    = lane >> 4;

    const int bid  = blockIdx.x;
    const int tok0 = bid * TPB;
    const int b    = tok0 >> 10;
    const int ph   = (tok0 >> 5) & 31;
    const int pw0  = tok0 & 31;               // 0 or 16

    const int dtile = bid >> 1;
    const int kh    = bid & 1;

    // ---- 1) pack-load: 128 cls x 16 dims -> LDS scatter (fragment order) ----
    if (t < 512) {
        const int cls  = kh * 128 + (t >> 2);
        const int quad = t & 3;
        const float4 v = *reinterpret_cast<const float4*>(
            table + (size_t)cls * DIM + dtile * 16 + quad * 4);
        const int ks = cls >> 5, gg = (cls >> 3) & 3, j = cls & 7;
        ushort* dst = pk + (ks & 3) * 512 + gg * 128 + j;
        dst[(quad * 4 + 0) * 8] = bf16rne(v.x);
        dst[(quad * 4 + 1) * 8] = bf16rne(v.y);
        dst[(quad * 4 + 2) * 8] = bf16rne(v.z);
        dst[(quad * 4 + 3) * 8] = bf16rne(v.w);
    }
    // ---- 2) zero hist ----
    for (int i = t; i < TPB * NCLS; i += NT) cnt[i] = 0u;
    __syncthreads();

    // ---- 3) pack copy-out: system-scope atomic dwords (bypass L2 -> coherent) ----
    {
        const unsigned val = (unsigned)pk[t * 2] | ((unsigned)pk[t * 2 + 1] << 16);
        __hip_atomic_store((unsigned*)Tt2 + (size_t)dtile * 2048 + kh * 1024 + t, val,
                           __ATOMIC_RELAXED, __HIP_MEMORY_SCOPE_SYSTEM);
    }
    __syncthreads();                          // drains every wave's stores (vmcnt 0)

    // ---- 4) publish pack completion (system-scope release) ----
    if (t == 0)
        __hip_atomic_store(&flags[bid], MAGIC, __ATOMIC_RELEASE, __HIP_MEMORY_SCOPE_SYSTEM);

    // ---- 5) histogram: 16 rows x 256 cols (16 patches), int4 per thread ----
    {
        const int row = t >> 6;               // 0..15
        const int col = (t & 63) * 4;         // 0..252
        const int4 q = *reinterpret_cast<const int4*>(
            smap + ((size_t)b * IMG + (size_t)(ph * 16 + row)) * IMG + pw0 * 16 + col);
        unsigned* hp = &cnt[(col >> 4) * NCLS];
        atomicAdd(&hp[min(max(q.x, 0), NCLS - 1)], 1u);
        atomicAdd(&hp[min(max(q.y, 0), NCLS - 1)], 1u);
        atomicAdd(&hp[min(max(q.z, 0), NCLS - 1)], 1u);
        atomicAdd(&hp[min(max(q.w, 0), NCLS - 1)], 1u);
    }
    __syncthreads();

    // ---- 6) counts -> bf16(count/256), exact ----
    for (int i = t; i < TPB * NCLS; i += NT)
        cntb[i >> 8][i & 255] = (ushort)(__float_as_uint((float)cnt[i] * (1.f / 256.f)) >> 16);

    // ---- 7) gate: RELAXED polls (no cache-inv storm), then ONE acquire ----
    if (t < 128) {
        while (__hip_atomic_load(&flags[t], __ATOMIC_RELAXED,
                                 __HIP_MEMORY_SCOPE_SYSTEM) != MAGIC) {}
    }
    __syncthreads();
    if (t == 0) {
        unsigned x = __hip_atomic_load(&flags[0], __ATOMIC_ACQUIRE,
                                       __HIP_MEMORY_SCOPE_SYSTEM);
        asm volatile("" :: "v"(x));           // keep the acquire load live
    }
    __syncthreads();

    // ---- 8) MFMA K-loop (verbatim R16) ----
    f32x4 acc[4];
    #pragma unroll
    for (int i = 0; i < 4; ++i) acc[i] = (f32x4){0.f, 0.f, 0.f, 0.f};

    const ushort* bt = Tt2 + (size_t)(w * 4) * 4096 + (size_t)lane * 8;
    #pragma unroll 2
    for (int ks = 0; ks < 8; ++ks) {
        const bf16x8 a = *reinterpret_cast<const bf16x8*>(&cntb[c][ks * 32 + g * 8]);
        bf16x8 bfv[4];
        #pragma unroll
        for (int nf = 0; nf < 4; ++nf)
            bfv[nf] = *reinterpret_cast<const bf16x8*>(bt + (size_t)nf * 4096 + ks * 512);
        #pragma unroll
        for (int nf = 0; nf < 4; ++nf)
            acc[nf] = __builtin_amdgcn_mfma_f32_16x16x32_bf16(a, bfv[nf], acc[nf], 0, 0, 0);
    }

    // ---- 9) pos-embed + LN partials (verbatim R16) ----
    const int quad   = w >> 2;
    const int cosSel = quad & 1;
    float ls[4]  = {0, 0, 0, 0};
    float ls2[4] = {0, 0, 0, 0};

    #pragma unroll
    for (int nf = 0; nf < 4; ++nf) {
        const int dlow = (w & 3) * 64 + nf * 16 + c;
        const float omega = exp2f((float)dlow * (-13.287712379549449f / 256.f));
        if (quad < 2) {
            float sv, cv; __sincosf((float)ph * omega, &sv, &cv);
            const float v = cosSel ? cv : sv;
            #pragma unroll
            for (int i = 0; i < 4; ++i) acc[nf][i] += v;
        } else {
            #pragma unroll
            for (int i = 0; i < 4; ++i) {
                float sv, cv; __sincosf((float)(pw0 + g * 4 + i) * omega, &sv, &cv);
                acc[nf][i] += cosSel ? cv : sv;
            }
        }
        #pragma unroll
        for (int i = 0; i < 4; ++i) { ls[i] += acc[nf][i]; ls2[i] += acc[nf][i] * acc[nf][i]; }
    }

    #pragma unroll
    for (int off = 1; off < 16; off <<= 1) {
        #pragma unroll
        for (int i = 0; i < 4; ++i) {
            ls[i]  += __shfl_xor(ls[i],  off, 64);
            ls2[i] += __shfl_xor(ls2[i], off, 64);
        }
    }
    if (c == 0) {
        #pragma unroll
        for (int i = 0; i < 4; ++i) { red[w][g][i][0] = ls[i]; red[w][g][i][1] = ls2[i]; }
    }
    __syncthreads();

    // ---- 10) finalize LN + store (verbatim R16) ----
    {
        float mu[4], rs[4];
        #pragma unroll
        for (int i = 0; i < 4; ++i) {
            float S = 0.f, S2 = 0.f;
            #pragma unroll
            for (int ww = 0; ww < 16; ++ww) { S += red[ww][g][i][0]; S2 += red[ww][g][i][1]; }
            mu[i] = S * (1.f / DIM);
            rs[i] = rsqrtf(S2 * (1.f / DIM) - mu[i] * mu[i] + 1e-5f);
        }
        #pragma unroll
        for (int nf = 0; nf < 4; ++nf) {
            const int d = w * 64 + nf * 16 + c;
            const float gv = gamma[d], bv = beta[d];
            #pragma unroll
            for (int i = 0; i < 4; ++i) {
                const int r = g * 4 + i;
                out[(size_t)(tok0 + r) * DIM + d] = (acc[nf][i] - mu[i]) * rs[i] * gv + bv;
            }
        }
    }
}

extern "C" void kernel_launch(void* const* d_in, const int* in_sizes, int n_in,
                              void* d_out, int out_size, void* d_ws, size_t ws_size,
                              hipStream_t stream) {
    const int*   smap  = (const int*)d_in[0];
    const float* table = (const float*)d_in[1];
    const float* gamma = (const float*)d_in[2];
    const float* beta  = (const float*)d_in[3];
    float*       out   = (float*)d_out;

    const int batches = in_sizes[0] / (IMG * IMG);       // = 2
    const int tokens  = batches * HPW * HPW;             // 2048
    const int nblk    = tokens / TPB;                    // 128

    ushort*   Tt2   = (ushort*)d_ws;                     // 512 KB packed table
    unsigned* flags = (unsigned*)(Tt2 + (size_t)64 * 4096);

    fused_one<<<nblk, NT, 0, stream>>>(smap, table, gamma, beta, out, Tt2, flags);
}